// Round 8
// baseline (165.233 us; speedup 1.0000x reference)
//
#include <hip/hip_runtime.h>
#include <hip/hip_bf16.h>

// Joint network: out[b,t,u,o] = tanh(enc_proj[b,t,:] + dec_proj[b,u,:] + b1) @ W2 + b2
// B=8 T=256 U=64 D=512 H=1024 O=128.  All I/O fp32.
//
// tanh identity: with C2L = 2*log2(e),
//   tanh(x) = 1 - 2/(2^(C2L*x) + 1),  2^(C2L*(e+d+b1)) = Ep * Dp
// Ep/Dp precomputed fp16 in the projection epilogue.
//
// joint_main R8: 32x32x16 MFMA (2x FLOP per B-fragment vs 16x16x32) + 2-t
// register reuse -> LDS reads per FLOP halved. Wave = 32u x 128o x 2t,
// acc = 2x4x16 = 128 AGPR, 2 waves/SIMD (ILP over TLP).
//
// ws: W1T f16 [1024][1024] @0 (2MiB) | W2T f16 [128][1024] @2MiB (256KiB)
//     Ep f16 [2048][1024] @2.25MiB (4MiB) | Dp f16 [512][1024] @6.25MiB (1MiB)

typedef _Float16 f16x8  __attribute__((ext_vector_type(8)));
typedef _Float16 f16x2  __attribute__((ext_vector_type(2)));
typedef float    f32x4  __attribute__((ext_vector_type(4)));
typedef float    f32x16 __attribute__((ext_vector_type(16)));

#define C2L 2.8853900817779268f

__device__ __forceinline__ float fast_exp2(float x) { return __builtin_amdgcn_exp2f(x); }

// v_cvt_pkrtz_f16_f32 returns __fp16x2 — bitcast to our _Float16x2
__device__ __forceinline__ f16x2 pk_cvt(float x, float y) {
    auto r = __builtin_amdgcn_cvt_pkrtz(x, y);
    union { decltype(r) a; f16x2 b; } c; c.a = r; return c.b;
}

// tanh on 8 packed f16 via pairwise reciprocal (4 rcph per 8).
// p = e*d + 1 in (1, inf); capped at 126 so q = p0*p1 <= 15876 keeps
// rq = rcph(q) in the f16 normal range.
__device__ __forceinline__ f16x8 tanh8(f16x8 e, f16x8 d) {
    const f16x8 one = {1,1,1,1,1,1,1,1};
    const f16x8 two = {2,2,2,2,2,2,2,2};
    const f16x8 cap = {126,126,126,126,126,126,126,126};
    union { f16x8 v; _Float16 s[8]; } p, r;
    p.v = e * d + one;                              // v_pk_fma_f16 x4
    p.v = __builtin_elementwise_min(p.v, cap);      // v_pk_min_f16 x4
    #pragma unroll
    for (int i = 0; i < 4; ++i) {
        _Float16 q  = p.s[2*i] * p.s[2*i+1];
        _Float16 rq = __builtin_amdgcn_rcph(q);
        r.s[2*i]   = p.s[2*i+1] * rq;               // = 1/p0
        r.s[2*i+1] = p.s[2*i]   * rq;               // = 1/p1
    }
    return one - two * r.v;                         // v_pk_fma_f16 x4
}

// async 16B global -> LDS (LDS dest is wave-uniform base + lane*16)
__device__ __forceinline__ void stage16(const void* g, void* l) {
    __builtin_amdgcn_global_load_lds(
        (const __attribute__((address_space(1))) unsigned int*)g,
        (__attribute__((address_space(3))) unsigned int*)l, 16, 0, 0);
}

// ---------------------------------------------------------------- transpose
// bx<32: W1 (1024x1024) -> W1T ; bx>=32: W2 (1024x128) -> W2T
__global__ __launch_bounds__(1024) void transpose_both(
    const float* __restrict__ W1, const float* __restrict__ W2,
    _Float16* __restrict__ W1T, _Float16* __restrict__ W2T)
{
    __shared__ float tile[32][33];
    int bx = blockIdx.x;
    const float* src; _Float16* dst; int C, c0;
    if (bx < 32) { src = W1; dst = W1T; C = 1024; c0 = bx * 32; }
    else         { src = W2; dst = W2T; C = 128;  c0 = (bx - 32) * 32; }
    int r0 = blockIdx.y * 32;
    int tx = threadIdx.x, ty = threadIdx.y;
    tile[ty][tx] = src[(r0 + ty) * C + (c0 + tx)];
    __syncthreads();
    dst[(size_t)(c0 + ty) * 1024 + (r0 + tx)] = (_Float16)tile[tx][ty];
}

// ---------------------------------------------------------------- projections
// rows 0..2047 -> Ep = 2^(C2L*(enc@W1[:512] + b1)); rows 2048.. -> Dp (dec, no bias)
__global__ __launch_bounds__(256) void proj_exp(
    const float* __restrict__ enc,     // [2048][512]
    const float* __restrict__ dec,     // [512][512]
    const _Float16* __restrict__ W1T,  // [1024][1024]
    const float* __restrict__ b1,      // [1024]
    _Float16* __restrict__ Ep,         // [2048][1024]
    _Float16* __restrict__ Dp)         // [512][1024]
{
    const int K = 512;
    int tid  = threadIdx.x;
    int w    = tid >> 6, lane = tid & 63;
    int quad = lane >> 4, l15 = lane & 15;
    int m_base = blockIdx.y * 64 + w * 16;
    int n_base = blockIdx.x * 64;

    bool is_enc = (m_base < 2048);
    const float* A = is_enc ? (enc + (size_t)(m_base + l15) * K)
                            : (dec + (size_t)(m_base - 2048 + l15) * K);
    int koff = is_enc ? 0 : 512;

    f32x4 acc[4] = {};
    for (int kc = 0; kc < K; kc += 32) {
        int k = kc + quad * 8;
        float4 a_lo = *reinterpret_cast<const float4*>(A + k);
        float4 a_hi = *reinterpret_cast<const float4*>(A + k + 4);
        union { f16x8 v; f16x2 h[4]; } a;
        a.h[0] = pk_cvt(a_lo.x, a_lo.y);
        a.h[1] = pk_cvt(a_lo.z, a_lo.w);
        a.h[2] = pk_cvt(a_hi.x, a_hi.y);
        a.h[3] = pk_cvt(a_hi.z, a_hi.w);
        #pragma unroll
        for (int f = 0; f < 4; ++f) {
            int n = n_base + f * 16 + l15;
            f16x8 b = *reinterpret_cast<const f16x8*>(W1T + n * 1024 + koff + k);
            acc[f] = __builtin_amdgcn_mfma_f32_16x16x32_f16(a.v, b, acc[f], 0, 0, 0);
        }
    }

    #pragma unroll
    for (int f = 0; f < 4; ++f) {
        int col = n_base + f * 16 + l15;
        float bv = is_enc ? b1[col] : 0.0f;
        #pragma unroll
        for (int v = 0; v < 4; ++v) {
            int row = m_base + quad * 4 + v;
            float val = fast_exp2(C2L * (acc[f][v] + bv));
            if (is_enc) Ep[(size_t)row * 1024 + col] = (_Float16)val;
            else        Dp[(size_t)(row - 2048) * 1024 + col] = (_Float16)val;
        }
    }
}

// ---------------------------------------------------------------- main fused
// Block = (b, 4 t): 4 waves; wave w: u-half (w&1)*32, t-pair (w>>1).
// Each wave: 32u x 128o x 2t via v_mfma_f32_32x32x16_f16.
//   A-frag: m=lane&31 (u), k=(lane>>5)*8+j  — computed in-register via tanh8
//   B-frag: n=lane&31 (o), k=(lane>>5)*8+j  — from double-buffered LDS (BK=64)
//   C/D   : col=lane&31, row=(reg&3)+8*(reg>>2)+4*(lane>>5)   [m74 verified]
// One barrier per tile; stage(it+1) issued right after barrier(it) so the
// vmcnt drain covers loads issued a full tile of compute earlier.
__global__ __launch_bounds__(256, 2) void joint_main(
    const _Float16* __restrict__ Ep,   // [2048][1024]
    const _Float16* __restrict__ Dp,   // [512][1024]
    const _Float16* __restrict__ W2T,  // [128][1024]
    const float* __restrict__ b2,      // [128]
    float* __restrict__ out)           // [8][256][64][128]
{
    __shared__ _Float16 sB[2][128 * 64];   // 2 x 16 KiB

    int b    = blockIdx.y;
    int tid  = threadIdx.x;
    int w    = tid >> 6, lane = tid & 63;
    int l31  = lane & 31, hi = lane >> 5;
    int u0   = (w & 1) * 32;
    int t0   = blockIdx.x * 4 + (w >> 1) * 2;

    const _Float16* ep0 = Ep + (size_t)(b * 256 + t0) * 1024 + hi * 8;
    const _Float16* ep1 = ep0 + 1024;
    const _Float16* dpr = Dp + (size_t)(b * 64 + u0 + l31) * 1024 + hi * 8;

    f32x16 acc0[4] = {}, acc1[4] = {};

    // stage tile 0 into buf 0 (1024 chunks of 16B, 4 per thread)
    #pragma unroll
    for (int i = 0; i < 4; ++i) {
        int c = i * 256 + tid;
        int row = c >> 3, kcs = c & 7;
        stage16(W2T + row * 1024 + ((kcs ^ (row & 7)) << 3),
                &sB[0][(i * 256 + (tid & 0xC0)) * 8]);
    }

    for (int it = 0; it < 16; ++it) {
        __syncthreads();   // drains stage(it) — issued one full tile ago
        if (it < 15) {
            int kb = (it + 1) * 64;
            _Float16* dst = sB[(it + 1) & 1];
            #pragma unroll
            for (int i = 0; i < 4; ++i) {
                int c = i * 256 + tid;
                int row = c >> 3, kcs = c & 7;
                stage16(W2T + row * 1024 + kb + ((kcs ^ (row & 7)) << 3),
                        dst + (i * 256 + (tid & 0xC0)) * 8);
            }
        }
        const _Float16* sb = sB[it & 1];
        #pragma unroll
        for (int k16 = 0; k16 < 4; ++k16) {
            int kg = it * 64 + k16 * 16;           // + hi*8 already in bases
            f16x8 dv = *reinterpret_cast<const f16x8*>(dpr + kg);
            f16x8 e0 = *reinterpret_cast<const f16x8*>(ep0 + kg);
            f16x8 e1 = *reinterpret_cast<const f16x8*>(ep1 + kg);
            f16x8 A0 = tanh8(e0, dv);
            f16x8 A1 = tanh8(e1, dv);
            int c = k16 * 2 + hi;                  // chunk index in row
            int sw = (c ^ (l31 & 7)) << 3;         // XOR de-swizzle
            #pragma unroll
            for (int of = 0; of < 4; ++of) {
                f16x8 bb = *reinterpret_cast<const f16x8*>(
                    sb + (of * 32 + l31) * 64 + sw);
                acc0[of] = __builtin_amdgcn_mfma_f32_32x32x16_f16(A0, bb, acc0[of], 0, 0, 0);
                acc1[of] = __builtin_amdgcn_mfma_f32_32x32x16_f16(A1, bb, acc1[of], 0, 0, 0);
            }
        }
    }

    float* o0 = out + ((size_t)(b * 256 + t0) * 64) * 128;
    float* o1 = o0 + 64 * 128;
    #pragma unroll
    for (int of = 0; of < 4; ++of) {
        int o = of * 32 + l31;
        float bv = b2[o];
        #pragma unroll
        for (int reg = 0; reg < 16; ++reg) {
            int u = u0 + (reg & 3) + 8 * (reg >> 2) + 4 * hi;
            o0[u * 128 + o] = acc0[of][reg] + bv;
            o1[u * 128 + o] = acc1[of][reg] + bv;
        }
    }
}

// ---------------------------------------------------------------- launch
extern "C" void kernel_launch(void* const* d_in, const int* in_sizes, int n_in,
                              void* d_out, int out_size, void* d_ws, size_t ws_size,
                              hipStream_t stream) {
    const float* enc = (const float*)d_in[0]; // [8][256][512]
    const float* dec = (const float*)d_in[1]; // [8][64][512]
    const float* W1  = (const float*)d_in[2]; // [1024][1024]
    const float* b1  = (const float*)d_in[3]; // [1024]
    const float* W2  = (const float*)d_in[4]; // [1024][128]
    const float* b2  = (const float*)d_in[5]; // [128]
    float* out = (float*)d_out;

    char* ws = (char*)d_ws;
    _Float16* W1T = (_Float16*)(ws);                               // 2 MiB
    _Float16* W2T = (_Float16*)(ws + (2u << 20));                  // 256 KiB
    _Float16* EpP = (_Float16*)(ws + (2u << 20) + (256u << 10));   // 4 MiB
    _Float16* DpP = (_Float16*)(ws + (6u << 20) + (256u << 10));   // 1 MiB

    transpose_both<<<dim3(36, 32), dim3(32, 32), 0, stream>>>(W1, W2, W1T, W2T);

    // fused projections + exp2 epilogue: M = 2048 (enc) + 512 (dec)
    proj_exp<<<dim3(16, 40), 256, 0, stream>>>(enc, dec, W1T, b1, EpP, DpP);

    joint_main<<<dim3(64, 8), 256, 0, stream>>>(EpP, DpP, W2T, b2, out);
}